// Round 1
// baseline (385.604 us; speedup 1.0000x reference)
//
#include <hip/hip_runtime.h>
#include <hip/hip_bf16.h>

#define H 768
#define NH 12
#define DH 64
#define LL 8
#define NTOK 16384   // B*S = 8*2048
#define NREL 100

typedef __attribute__((ext_vector_type(8))) short short8;
typedef __attribute__((ext_vector_type(4))) float f32x4;

__device__ __forceinline__ float bf2f(ushort u) {
  union { unsigned int i; float f; } v; v.i = ((unsigned int)u) << 16; return v.f;
}
__device__ __forceinline__ ushort f2bf(float f) {
  union { float f; unsigned int i; } v; v.f = f;
  unsigned int x = v.i;
  return (ushort)((x + 0x7fffu + ((x >> 16) & 1u)) >> 16);  // RNE
}

// ---------------------------------------------------------------- cvt f32->bf16
__global__ __launch_bounds__(256) void cvt_kernel(const float* __restrict__ src,
                                                  ushort* __restrict__ dst) {
  int i = (blockIdx.x * 256 + threadIdx.x) * 4;
  float4 v = *(const float4*)(src + i);
  ushort4 o; o.x = f2bf(v.x); o.y = f2bf(v.y); o.z = f2bf(v.z); o.w = f2bf(v.w);
  *(ushort4*)(dst + i) = o;
}

// ------------------------------------------------- transpose [H][H] f32 -> bf16
__global__ __launch_bounds__(256) void transpose_bf16_kernel(const float* __restrict__ src,
                                                             ushort* __restrict__ dst) {
  __shared__ float tile[32][33];
  int bx = blockIdx.x * 32, by = blockIdx.y * 32;
  int tx = threadIdx.x & 31, ty = threadIdx.x >> 5;  // ty 0..7
  #pragma unroll
  for (int i = 0; i < 32; i += 8)
    tile[ty + i][tx] = src[(size_t)(by + ty + i) * H + bx + tx];
  __syncthreads();
  #pragma unroll
  for (int i = 0; i < 32; i += 8)
    dst[(size_t)(bx + ty + i) * H + by + tx] = f2bf(tile[tx][ty + i]);
}

// --------------------------------------- K/V tables: rel_table @ Wk/Wv + bias
#define RC 10
__global__ __launch_bounds__(256) void kv_table_kernel(
    const float* __restrict__ rel_table,
    const float* __restrict__ Wk, const float* __restrict__ bk,
    const float* __restrict__ Wv, const float* __restrict__ bv,
    ushort* __restrict__ Ktab, ushort* __restrict__ Vtab) {
  __shared__ float a[RC][H];   // 30 KB
  int h = blockIdx.x * 256 + threadIdx.x;
  int r0 = blockIdx.y * RC;
  for (int i = threadIdx.x; i < RC * H; i += 256)
    a[i / H][i % H] = rel_table[(size_t)r0 * H + i];
  __syncthreads();
  float sk[RC], sv[RC];
  #pragma unroll
  for (int rr = 0; rr < RC; ++rr) { sk[rr] = 0.f; sv[rr] = 0.f; }
  for (int k = 0; k < H; ++k) {
    float wk = Wk[(size_t)k * H + h], wv = Wv[(size_t)k * H + h];
    #pragma unroll
    for (int rr = 0; rr < RC; ++rr) { sk[rr] += a[rr][k] * wk; sv[rr] += a[rr][k] * wv; }
  }
  float bkh = bk[h], bvh = bv[h];
  #pragma unroll
  for (int rr = 0; rr < RC; ++rr) {
    Ktab[(size_t)(r0 + rr) * H + h] = f2bf(sk[rr] + bkh);
    Vtab[(size_t)(r0 + rr) * H + h] = f2bf(sv[rr] + bvh);
  }
}

// ------------------------------------------------------------- bf16 MFMA GEMM
// C[M][N] = A[M][K] @ Bt[N][K]^T + bias, all bf16 in / bf16 out, fp32 accum.
__device__ __forceinline__ void gload_lds16(const void* g, void* l) {
  __builtin_amdgcn_global_load_lds(
      (const __attribute__((address_space(1))) unsigned int*)g,
      (__attribute__((address_space(3))) unsigned int*)l, 16, 0, 0);
}

#define BM 128
#define BN 128
#define BK 32

__global__ __launch_bounds__(256, 2) void gemm_bt_kernel(
    const ushort* __restrict__ A,    // [M][K]
    const ushort* __restrict__ Bt,   // [N][K]
    const float* __restrict__ bias,  // [N]
    ushort* __restrict__ C,          // [M][N]
    int M, int N, int K) {
  __shared__ ushort As[BM * BK];   // 8 KB, row-major [BM][BK]
  __shared__ ushort Bs[BN * BK];   // 8 KB
  const int tid = threadIdx.x;
  const int row0 = blockIdx.y * BM;
  const int col0 = blockIdx.x * BN;
  const int wave = tid >> 6;
  const int lane = tid & 63;
  const int wr = wave >> 1, wc = wave & 1;     // 2x2 waves, 64x64 each
  const int lr = lane & 15, lk = lane >> 4;    // frag row/col & k-group
  f32x4 acc[4][4];
  #pragma unroll
  for (int m = 0; m < 4; ++m)
    #pragma unroll
    for (int n = 0; n < 4; ++n) acc[m][n] = (f32x4)(0.f);

  for (int k0 = 0; k0 < K; k0 += BK) {
    #pragma unroll
    for (int i = 0; i < 2; ++i) {
      int c = tid + i * 256;        // 16B chunk id, 512 chunks per 8KB tile
      int r = c >> 2, q = c & 3;    // tile row, quarter-row (8 bf16)
      gload_lds16(A  + (size_t)(row0 + r) * K + k0 + q * 8, (char*)As + c * 16);
      gload_lds16(Bt + (size_t)(col0 + r) * K + k0 + q * 8, (char*)Bs + c * 16);
    }
    __syncthreads();
    short8 af[4], bfr[4];
    #pragma unroll
    for (int m = 0; m < 4; ++m)
      af[m] = *(const short8*)(As + (wr * 64 + m * 16 + lr) * BK + lk * 8);
    #pragma unroll
    for (int n = 0; n < 4; ++n)
      bfr[n] = *(const short8*)(Bs + (wc * 64 + n * 16 + lr) * BK + lk * 8);
    #pragma unroll
    for (int m = 0; m < 4; ++m)
      #pragma unroll
      for (int n = 0; n < 4; ++n)
        acc[m][n] = __builtin_amdgcn_mfma_f32_16x16x32_bf16(af[m], bfr[n], acc[m][n], 0, 0, 0);
    __syncthreads();
  }
  // epilogue: C/D layout col = lane&15, row = (lane>>4)*4 + j  [verified m89/m91]
  #pragma unroll
  for (int m = 0; m < 4; ++m) {
    #pragma unroll
    for (int n = 0; n < 4; ++n) {
      int col = col0 + wc * 64 + n * 16 + lr;
      float b = bias[col];
      #pragma unroll
      for (int j = 0; j < 4; ++j) {
        int row = row0 + wr * 64 + m * 16 + lk * 4 + j;
        C[(size_t)row * N + col] = f2bf(acc[m][n][j] + b);
      }
    }
  }
}

// ------------------------------------------------- fused 8-leaf GAT attention
// One 16-lane group per (token, head); lane j owns dims [4j, 4j+4).
__global__ __launch_bounds__(256) void attn_kernel(
    const ushort* __restrict__ Q,     // [NTOK][H] bf16
    const ushort* __restrict__ Ktab,  // [NREL][H] bf16
    const ushort* __restrict__ Vtab,  // [NREL][H] bf16
    const int* __restrict__ graph,    // [NTOK][LL]
    const int* __restrict__ relid,    // [NTOK][LL]
    ushort* __restrict__ Ctx) {       // [NTOK][H] bf16
  int g = blockIdx.x * 16 + (threadIdx.x >> 4);
  int j = threadIdx.x & 15;
  int t = g / NH, n = g % NH;
  const int base = n * DH + j * 4;
  ushort4 q4 = *(const ushort4*)(Q + (size_t)t * H + base);
  float q0 = bf2f(q4.x), q1 = bf2f(q4.y), q2 = bf2f(q4.z), q3 = bf2f(q4.w);
  int rid[LL]; float sc[LL];
  #pragma unroll
  for (int l = 0; l < LL; ++l) {
    int gs = graph[t * LL + l];
    int r = relid[t * LL + l]; r = r < 0 ? 0 : r;
    rid[l] = r;
    ushort4 k4 = *(const ushort4*)(Ktab + (size_t)r * H + base);
    float s = q0 * bf2f(k4.x) + q1 * bf2f(k4.y) + q2 * bf2f(k4.z) + q3 * bf2f(k4.w);
    s += __shfl_xor(s, 1, 16);
    s += __shfl_xor(s, 2, 16);
    s += __shfl_xor(s, 4, 16);
    s += __shfl_xor(s, 8, 16);
    sc[l] = (gs != -1) ? s * 0.125f : -10000.0f;   // 1/sqrt(64)
  }
  float mx = sc[0];
  #pragma unroll
  for (int l = 1; l < LL; ++l) mx = fmaxf(mx, sc[l]);
  float p[LL], den = 0.f;
  #pragma unroll
  for (int l = 0; l < LL; ++l) { p[l] = __expf(sc[l] - mx); den += p[l]; }
  float inv = 1.f / den;
  float a0 = 0, a1 = 0, a2 = 0, a3 = 0;
  #pragma unroll
  for (int l = 0; l < LL; ++l) {
    ushort4 v4 = *(const ushort4*)(Vtab + (size_t)rid[l] * H + base);
    float pl = p[l] * inv;
    a0 += pl * bf2f(v4.x); a1 += pl * bf2f(v4.y);
    a2 += pl * bf2f(v4.z); a3 += pl * bf2f(v4.w);
  }
  ushort4 o; o.x = f2bf(a0); o.y = f2bf(a1); o.z = f2bf(a2); o.w = f2bf(a3);
  *(ushort4*)(Ctx + (size_t)t * H + base) = o;
}

// ------------------------------------------------------- residual + LayerNorm
__global__ __launch_bounds__(256) void ln_kernel(
    const float* __restrict__ text, const ushort* __restrict__ op,
    const float* __restrict__ gamma, const float* __restrict__ beta,
    float* __restrict__ out) {
  int t = blockIdx.x;
  const float* xr = text + (size_t)t * H;
  const ushort* orow = op + (size_t)t * H;
  float x[3]; float s = 0.f, s2 = 0.f;
  #pragma unroll
  for (int jj = 0; jj < 3; ++jj) {
    int c = threadIdx.x + jj * 256;
    float v = xr[c] + bf2f(orow[c]);
    x[jj] = v; s += v; s2 += v * v;
  }
  #pragma unroll
  for (int off = 32; off > 0; off >>= 1) {
    s  += __shfl_xor(s, off, 64);
    s2 += __shfl_xor(s2, off, 64);
  }
  __shared__ float red[2][4];
  int wave = threadIdx.x >> 6, lane = threadIdx.x & 63;
  if (lane == 0) { red[0][wave] = s; red[1][wave] = s2; }
  __syncthreads();
  s  = red[0][0] + red[0][1] + red[0][2] + red[0][3];
  s2 = red[1][0] + red[1][1] + red[1][2] + red[1][3];
  float mu = s * (1.f / H);
  float var = s2 * (1.f / H) - mu * mu;
  float rs = rsqrtf(var + 1e-5f);
  #pragma unroll
  for (int jj = 0; jj < 3; ++jj) {
    int c = threadIdx.x + jj * 256;
    out[(size_t)t * H + c] = (x[jj] - mu) * rs * gamma[c] + beta[c];
  }
}

// ---------------------------------------------------------------------- driver
extern "C" void kernel_launch(void* const* d_in, const int* in_sizes, int n_in,
                              void* d_out, int out_size, void* d_ws, size_t ws_size,
                              hipStream_t stream) {
  const float* text      = (const float*)d_in[0];
  const int*   graph     = (const int*)d_in[1];
  const int*   relid     = (const int*)d_in[2];
  const float* rel_table = (const float*)d_in[3];
  const float* Wq = (const float*)d_in[4];  const float* bq = (const float*)d_in[5];
  const float* Wk = (const float*)d_in[6];  const float* bk = (const float*)d_in[7];
  const float* Wv = (const float*)d_in[8];  const float* bv = (const float*)d_in[9];
  const float* Wo = (const float*)d_in[10]; const float* bo = (const float*)d_in[11];
  const float* gamma = (const float*)d_in[12];
  const float* beta  = (const float*)d_in[13];
  float* out = (float*)d_out;
  char* ws = (char*)d_ws;

  const size_t TOKH = (size_t)NTOK * H;           // 12,582,912
  ushort* Xbf  = (ushort*)(ws);                   // 25.2 MB; later reused as Ctx
  ushort* Qbf  = (ushort*)(ws + TOKH * 2);        // 25.2 MB; later reused as OutProj
  ushort* WqT  = (ushort*)(ws + TOKH * 4);                         // 1.18 MB
  ushort* WoT  = (ushort*)(ws + TOKH * 4 + (size_t)H * H * 2);     // 1.18 MB
  ushort* Ktab = (ushort*)(ws + TOKH * 4 + (size_t)H * H * 4);     // 150 KB
  ushort* Vtab = (ushort*)(ws + TOKH * 4 + (size_t)H * H * 4 + (size_t)NREL * H * 2);

  // 1) X -> bf16
  cvt_kernel<<<TOKH / 1024, 256, 0, stream>>>(text, Xbf);
  // 2) transpose weights -> bf16 [N][K]
  dim3 tg(H / 32, H / 32);
  transpose_bf16_kernel<<<tg, 256, 0, stream>>>(Wq, WqT);
  transpose_bf16_kernel<<<tg, 256, 0, stream>>>(Wo, WoT);
  // 3) K/V tables
  dim3 kvg(H / 256, NREL / RC);
  kv_table_kernel<<<kvg, 256, 0, stream>>>(rel_table, Wk, bk, Wv, bv, Ktab, Vtab);
  // 4) Q = Xbf @ WqT^T + bq
  dim3 g1(H / BN, NTOK / BM);
  gemm_bt_kernel<<<g1, 256, 0, stream>>>(Xbf, WqT, bq, Qbf, NTOK, H, H);
  // 5) attention -> Ctx (reuse Xbf storage)
  attn_kernel<<<(NTOK * NH) / 16, 256, 0, stream>>>(Qbf, Ktab, Vtab, graph, relid, Xbf);
  // 6) OutProj = Ctx @ WoT^T + bo (reuse Qbf storage)
  gemm_bt_kernel<<<g1, 256, 0, stream>>>(Xbf, WoT, bo, Qbf, NTOK, H, H);
  // 7) residual + LayerNorm -> out
  ln_kernel<<<NTOK, 256, 0, stream>>>(text, Qbf, gamma, beta, out);
}

// Round 2
// 182.415 us; speedup vs baseline: 2.1139x; 2.1139x over previous
//
#include <hip/hip_runtime.h>
#include <hip/hip_bf16.h>

#define H 768
#define NH 12
#define DH 64
#define LL 8
#define NTOK 16384   // B*S = 8*2048
#define NREL 100
#define NRELP 128    // padded to BM

typedef __attribute__((ext_vector_type(8))) short short8;
typedef __attribute__((ext_vector_type(4))) float f32x4;

__device__ __forceinline__ float bf2f(ushort u) {
  union { unsigned int i; float f; } v; v.i = ((unsigned int)u) << 16; return v.f;
}
__device__ __forceinline__ ushort f2bf(float f) {
  union { float f; unsigned int i; } v; v.f = f;
  unsigned int x = v.i;
  return (ushort)((x + 0x7fffu + ((x >> 16) & 1u)) >> 16);  // RNE
}

// ---------------------------------------------------------------- cvt f32->bf16
__global__ __launch_bounds__(256) void cvt_kernel(const float* __restrict__ src,
                                                  ushort* __restrict__ dst) {
  int i = (blockIdx.x * 256 + threadIdx.x) * 4;
  float4 v = *(const float4*)(src + i);
  ushort4 o; o.x = f2bf(v.x); o.y = f2bf(v.y); o.z = f2bf(v.z); o.w = f2bf(v.w);
  *(ushort4*)(dst + i) = o;
}

// -------------------------------- rel_table [100][768] f32 -> [128][768] bf16
__global__ __launch_bounds__(256) void rel_cvt_kernel(const float* __restrict__ src,
                                                      ushort* __restrict__ dst) {
  int i = blockIdx.x * 256 + threadIdx.x;      // 0 .. 128*768-1
  int row = i / H;
  dst[i] = (row < NREL) ? f2bf(src[i]) : (ushort)0;
}

// ------------------------------------------------- transpose [H][H] f32 -> bf16
__global__ __launch_bounds__(256) void transpose_bf16_kernel(const float* __restrict__ src,
                                                             ushort* __restrict__ dst) {
  __shared__ float tile[32][33];
  int bx = blockIdx.x * 32, by = blockIdx.y * 32;
  int tx = threadIdx.x & 31, ty = threadIdx.x >> 5;  // ty 0..7
  #pragma unroll
  for (int i = 0; i < 32; i += 8)
    tile[ty + i][tx] = src[(size_t)(by + ty + i) * H + bx + tx];
  __syncthreads();
  #pragma unroll
  for (int i = 0; i < 32; i += 8)
    dst[(size_t)(bx + ty + i) * H + by + tx] = f2bf(tile[tx][ty + i]);
}

// ------------------------------------------------------------- bf16 MFMA GEMM
// C[M][N] = A[M][K] @ Bt[N][K]^T + bias, all bf16 in / bf16 out, fp32 accum.
__device__ __forceinline__ void gload_lds16(const void* g, void* l) {
  __builtin_amdgcn_global_load_lds(
      (const __attribute__((address_space(1))) unsigned int*)g,
      (__attribute__((address_space(3))) unsigned int*)l, 16, 0, 0);
}

#define BM 128
#define BN 128
#define BK 32

__global__ __launch_bounds__(256, 2) void gemm_bt_kernel(
    const ushort* __restrict__ A,    // [M][K]
    const ushort* __restrict__ Bt,   // [N][K]
    const float* __restrict__ bias,  // [N]
    ushort* __restrict__ C,          // [M][N]
    int M, int N, int K) {
  __shared__ ushort As[BM * BK];   // 8 KB, row-major [BM][BK]
  __shared__ ushort Bs[BN * BK];   // 8 KB
  const int tid = threadIdx.x;
  const int row0 = blockIdx.y * BM;
  const int col0 = blockIdx.x * BN;
  const int wave = tid >> 6;
  const int lane = tid & 63;
  const int wr = wave >> 1, wc = wave & 1;     // 2x2 waves, 64x64 each
  const int lr = lane & 15, lk = lane >> 4;    // frag row/col & k-group
  f32x4 acc[4][4];
  #pragma unroll
  for (int m = 0; m < 4; ++m)
    #pragma unroll
    for (int n = 0; n < 4; ++n) acc[m][n] = (f32x4)(0.f);

  for (int k0 = 0; k0 < K; k0 += BK) {
    #pragma unroll
    for (int i = 0; i < 2; ++i) {
      int c = tid + i * 256;        // 16B chunk id, 512 chunks per 8KB tile
      int r = c >> 2, q = c & 3;    // tile row, quarter-row (8 bf16)
      gload_lds16(A  + (size_t)(row0 + r) * K + k0 + q * 8, (char*)As + c * 16);
      gload_lds16(Bt + (size_t)(col0 + r) * K + k0 + q * 8, (char*)Bs + c * 16);
    }
    __syncthreads();
    short8 af[4], bfr[4];
    #pragma unroll
    for (int m = 0; m < 4; ++m)
      af[m] = *(const short8*)(As + (wr * 64 + m * 16 + lr) * BK + lk * 8);
    #pragma unroll
    for (int n = 0; n < 4; ++n)
      bfr[n] = *(const short8*)(Bs + (wc * 64 + n * 16 + lr) * BK + lk * 8);
    #pragma unroll
    for (int m = 0; m < 4; ++m)
      #pragma unroll
      for (int n = 0; n < 4; ++n)
        acc[m][n] = __builtin_amdgcn_mfma_f32_16x16x32_bf16(af[m], bfr[n], acc[m][n], 0, 0, 0);
    __syncthreads();
  }
  // epilogue: C/D layout col = lane&15, row = (lane>>4)*4 + j  [verified m89/m91]
  #pragma unroll
  for (int m = 0; m < 4; ++m) {
    #pragma unroll
    for (int n = 0; n < 4; ++n) {
      int col = col0 + wc * 64 + n * 16 + lr;
      float b = bias[col];
      #pragma unroll
      for (int j = 0; j < 4; ++j) {
        int row = row0 + wr * 64 + m * 16 + lk * 4 + j;
        C[(size_t)row * N + col] = f2bf(acc[m][n][j] + b);
      }
    }
  }
}

// ------------------------------------------------- fused 8-leaf GAT attention
// One 16-lane group per (token, head); lane j owns dims [4j, 4j+4).
__global__ __launch_bounds__(256) void attn_kernel(
    const ushort* __restrict__ Q,     // [NTOK][H] bf16
    const ushort* __restrict__ Ktab,  // [>=NREL][H] bf16
    const ushort* __restrict__ Vtab,  // [>=NREL][H] bf16
    const int* __restrict__ graph,    // [NTOK][LL]
    const int* __restrict__ relid,    // [NTOK][LL]
    ushort* __restrict__ Ctx) {       // [NTOK][H] bf16
  int g = blockIdx.x * 16 + (threadIdx.x >> 4);
  int j = threadIdx.x & 15;
  int t = g / NH, n = g % NH;
  const int base = n * DH + j * 4;
  ushort4 q4 = *(const ushort4*)(Q + (size_t)t * H + base);
  float q0 = bf2f(q4.x), q1 = bf2f(q4.y), q2 = bf2f(q4.z), q3 = bf2f(q4.w);
  int rid[LL]; float sc[LL];
  #pragma unroll
  for (int l = 0; l < LL; ++l) {
    int gs = graph[t * LL + l];
    int r = relid[t * LL + l]; r = r < 0 ? 0 : r;
    rid[l] = r;
    ushort4 k4 = *(const ushort4*)(Ktab + (size_t)r * H + base);
    float s = q0 * bf2f(k4.x) + q1 * bf2f(k4.y) + q2 * bf2f(k4.z) + q3 * bf2f(k4.w);
    s += __shfl_xor(s, 1, 16);
    s += __shfl_xor(s, 2, 16);
    s += __shfl_xor(s, 4, 16);
    s += __shfl_xor(s, 8, 16);
    sc[l] = (gs != -1) ? s * 0.125f : -10000.0f;   // 1/sqrt(64)
  }
  float mx = sc[0];
  #pragma unroll
  for (int l = 1; l < LL; ++l) mx = fmaxf(mx, sc[l]);
  float p[LL], den = 0.f;
  #pragma unroll
  for (int l = 0; l < LL; ++l) { p[l] = __expf(sc[l] - mx); den += p[l]; }
  float inv = 1.f / den;
  float a0 = 0, a1 = 0, a2 = 0, a3 = 0;
  #pragma unroll
  for (int l = 0; l < LL; ++l) {
    ushort4 v4 = *(const ushort4*)(Vtab + (size_t)rid[l] * H + base);
    float pl = p[l] * inv;
    a0 += pl * bf2f(v4.x); a1 += pl * bf2f(v4.y);
    a2 += pl * bf2f(v4.z); a3 += pl * bf2f(v4.w);
  }
  ushort4 o; o.x = f2bf(a0); o.y = f2bf(a1); o.z = f2bf(a2); o.w = f2bf(a3);
  *(ushort4*)(Ctx + (size_t)t * H + base) = o;
}

// ------------------------------------------------------- residual + LayerNorm
__global__ __launch_bounds__(256) void ln_kernel(
    const float* __restrict__ text, const ushort* __restrict__ op,
    const float* __restrict__ gamma, const float* __restrict__ beta,
    float* __restrict__ out) {
  int t = blockIdx.x;
  const float* xr = text + (size_t)t * H;
  const ushort* orow = op + (size_t)t * H;
  float x[3]; float s = 0.f, s2 = 0.f;
  #pragma unroll
  for (int jj = 0; jj < 3; ++jj) {
    int c = threadIdx.x + jj * 256;
    float v = xr[c] + bf2f(orow[c]);
    x[jj] = v; s += v; s2 += v * v;
  }
  #pragma unroll
  for (int off = 32; off > 0; off >>= 1) {
    s  += __shfl_xor(s, off, 64);
    s2 += __shfl_xor(s2, off, 64);
  }
  __shared__ float red[2][4];
  int wave = threadIdx.x >> 6, lane = threadIdx.x & 63;
  if (lane == 0) { red[0][wave] = s; red[1][wave] = s2; }
  __syncthreads();
  s  = red[0][0] + red[0][1] + red[0][2] + red[0][3];
  s2 = red[1][0] + red[1][1] + red[1][2] + red[1][3];
  float mu = s * (1.f / H);
  float var = s2 * (1.f / H) - mu * mu;
  float rs = rsqrtf(var + 1e-5f);
  #pragma unroll
  for (int jj = 0; jj < 3; ++jj) {
    int c = threadIdx.x + jj * 256;
    out[(size_t)t * H + c] = (x[jj] - mu) * rs * gamma[c] + beta[c];
  }
}

// ---------------------------------------------------------------------- driver
extern "C" void kernel_launch(void* const* d_in, const int* in_sizes, int n_in,
                              void* d_out, int out_size, void* d_ws, size_t ws_size,
                              hipStream_t stream) {
  const float* text      = (const float*)d_in[0];
  const int*   graph     = (const int*)d_in[1];
  const int*   relid     = (const int*)d_in[2];
  const float* rel_table = (const float*)d_in[3];
  const float* Wq = (const float*)d_in[4];  const float* bq = (const float*)d_in[5];
  const float* Wk = (const float*)d_in[6];  const float* bk = (const float*)d_in[7];
  const float* Wv = (const float*)d_in[8];  const float* bv = (const float*)d_in[9];
  const float* Wo = (const float*)d_in[10]; const float* bo = (const float*)d_in[11];
  const float* gamma = (const float*)d_in[12];
  const float* beta  = (const float*)d_in[13];
  float* out = (float*)d_out;
  char* ws = (char*)d_ws;

  const size_t TOKH = (size_t)NTOK * H;           // 12,582,912
  size_t off = 0;
  ushort* Xbf  = (ushort*)(ws + off); off += TOKH * 2;             // 25.2 MB; reused as Ctx
  ushort* Qbf  = (ushort*)(ws + off); off += TOKH * 2;             // 25.2 MB; reused as OutProj
  ushort* WqT  = (ushort*)(ws + off); off += (size_t)H * H * 2;    // 1.18 MB
  ushort* WoT  = (ushort*)(ws + off); off += (size_t)H * H * 2;
  ushort* WkT  = (ushort*)(ws + off); off += (size_t)H * H * 2;
  ushort* WvT  = (ushort*)(ws + off); off += (size_t)H * H * 2;
  ushort* RelB = (ushort*)(ws + off); off += (size_t)NRELP * H * 2;  // 196 KB
  ushort* Ktab = (ushort*)(ws + off); off += (size_t)NRELP * H * 2;
  ushort* Vtab = (ushort*)(ws + off); off += (size_t)NRELP * H * 2;

  // 1) X -> bf16; rel_table -> padded bf16
  cvt_kernel<<<TOKH / 1024, 256, 0, stream>>>(text, Xbf);
  rel_cvt_kernel<<<(NRELP * H) / 256, 256, 0, stream>>>(rel_table, RelB);
  // 2) transpose weights -> bf16 [N][K]
  dim3 tg(H / 32, H / 32);
  transpose_bf16_kernel<<<tg, 256, 0, stream>>>(Wq, WqT);
  transpose_bf16_kernel<<<tg, 256, 0, stream>>>(Wo, WoT);
  transpose_bf16_kernel<<<tg, 256, 0, stream>>>(Wk, WkT);
  transpose_bf16_kernel<<<tg, 256, 0, stream>>>(Wv, WvT);
  // 3) K/V tables via MFMA: [128][768] @ [768][768]^T
  dim3 gkv(H / BN, NRELP / BM);
  gemm_bt_kernel<<<gkv, 256, 0, stream>>>(RelB, WkT, bk, Ktab, NRELP, H, H);
  gemm_bt_kernel<<<gkv, 256, 0, stream>>>(RelB, WvT, bv, Vtab, NRELP, H, H);
  // 4) Q = Xbf @ WqT^T + bq
  dim3 g1(H / BN, NTOK / BM);
  gemm_bt_kernel<<<g1, 256, 0, stream>>>(Xbf, WqT, bq, Qbf, NTOK, H, H);
  // 5) attention -> Ctx (reuse Xbf storage)
  attn_kernel<<<(NTOK * NH) / 16, 256, 0, stream>>>(Qbf, Ktab, Vtab, graph, relid, Xbf);
  // 6) OutProj = Ctx @ WoT^T + bo (reuse Qbf storage)
  gemm_bt_kernel<<<g1, 256, 0, stream>>>(Xbf, WoT, bo, Qbf, NTOK, H, H);
  // 7) residual + LayerNorm -> out
  ln_kernel<<<NTOK, 256, 0, stream>>>(text, Qbf, gamma, beta, out);
}